// Round 5
// baseline (265.070 us; speedup 1.0000x reference)
//
#include <hip/hip_runtime.h>
#include <hip/hip_bf16.h>
#include <math.h>

#define Bq 4
#define Lq 2048
#define Dq 512
#define Hq 8
#define DKq 64
#define Uq 24
#define TSCAN 16
#define NTILE (Lq / TSCAN)   // 128
#define NSUP 16              // supertiles (8 tiles each)
#define JCH 128              // softmax j-chunk
#define NCH (Lq / JCH)       // 16
#define TKCH 8               // m-chunks per thread in topk (2048/256)

typedef unsigned short ushort_t;
typedef unsigned long long u64;
typedef __attribute__((ext_vector_type(8))) short bfrag8;   // 8 bf16 (4 VGPRs)
typedef __attribute__((ext_vector_type(4))) float facc4;    // MFMA accumulator

__device__ inline ushort_t bf16_rne(float f) {
  unsigned u = __float_as_uint(f);
  u += 0x7FFF + ((u >> 16) & 1);
  return (ushort_t)(u >> 16);
}
__device__ inline float bf16f(ushort_t h) {
  return __uint_as_float(((unsigned)h) << 16);
}
// monotone float -> uint map (no NaNs in inputs)
__device__ inline unsigned fkey(float f) {
  unsigned u = __float_as_uint(f);
  return (u & 0x80000000u) ? ~u : (u | 0x80000000u);
}
// async global->LDS, 16B per lane (lds dest = wave base + lane*16)
__device__ __forceinline__ void gl2lds16(const void* g, void* l) {
  __builtin_amdgcn_global_load_lds(
      (const __attribute__((address_space(1))) unsigned*)g,
      (__attribute__((address_space(3))) unsigned*)l, 16, 0, 0);
}

// ---------------------------------------------------------------------------
// prep_all: ONE launch for all input prep.
// y=0: q->hi/lo, y=1: k->hi/lo, y=2: v->hi (activation casts)
// y=3: weight transpose+cast (first 1024 blocks; z=bx>>8 picks W)
// ---------------------------------------------------------------------------
__global__ __launch_bounds__(256) void prep_all(
    const float* __restrict__ xq, const float* __restrict__ xk,
    const float* __restrict__ xv, ushort_t* __restrict__ qh,
    ushort_t* __restrict__ ql, ushort_t* __restrict__ kh,
    ushort_t* __restrict__ kl, ushort_t* __restrict__ vh,
    const float* __restrict__ W0, const float* __restrict__ W1,
    const float* __restrict__ W2, const float* __restrict__ W3,
    ushort_t* __restrict__ T0h, ushort_t* __restrict__ T0l,
    ushort_t* __restrict__ T1h, ushort_t* __restrict__ T1l,
    ushort_t* __restrict__ T2h, ushort_t* __restrict__ T3h) {
  __shared__ float tile[32][33];
  int y = blockIdx.y;
  if (y < 3) {
    const float* x = y == 0 ? xq : (y == 1 ? xk : xv);
    ushort_t* hi = y == 0 ? qh : (y == 1 ? kh : vh);
    ushort_t* lo = y == 0 ? ql : kl;  // unused for y==2
    int t = blockIdx.x * 256 + threadIdx.x;
    float4 v = *(const float4*)&x[(size_t)t * 4];
    ushort_t h0 = bf16_rne(v.x), h1 = bf16_rne(v.y), h2 = bf16_rne(v.z),
             h3 = bf16_rne(v.w);
    ushort4 hh = {h0, h1, h2, h3};
    *(ushort4*)&hi[(size_t)t * 4] = hh;
    if (y < 2) {
      ushort4 ll = {bf16_rne(v.x - bf16f(h0)), bf16_rne(v.y - bf16f(h1)),
                    bf16_rne(v.z - bf16f(h2)), bf16_rne(v.w - bf16f(h3))};
      *(ushort4*)&lo[(size_t)t * 4] = ll;
    }
    return;
  }
  // weight transpose path: 1024 working blocks
  int id = blockIdx.x;
  if (id >= 1024) return;
  int z = id >> 8;
  const float* W = z == 0 ? W0 : (z == 1 ? W1 : (z == 2 ? W2 : W3));
  ushort_t* Th = z == 0 ? T0h : (z == 1 ? T1h : (z == 2 ? T2h : T3h));
  ushort_t* Tl = z == 0 ? T0l : (z == 1 ? T1l : nullptr);
  int k0 = ((id >> 4) & 15) * 32, n0 = (id & 15) * 32;
  int tx = threadIdx.x & 31, ty = threadIdx.x >> 5;  // ty 0..7
  for (int r = ty; r < 32; r += 8)
    tile[tx][r] = W[(size_t)(k0 + r) * 512 + n0 + tx];
  __syncthreads();
  for (int r = ty; r < 32; r += 8) {
    float v = tile[r][tx];
    ushort_t h = bf16_rne(v);
    Th[(size_t)(n0 + r) * 512 + k0 + tx] = h;
    if (Tl) Tl[(size_t)(n0 + r) * 512 + k0 + tx] = bf16_rne(v - bf16f(h));
  }
}

// ---------------------------------------------------------------------------
// Fused Q/K/V projection GEMM, 64x128 tile, 4 waves x (32x64).
// z=0: Q (split-bf16), z=1: K (split), z=2: V (plain hi).
// Re-tiled 128x128 -> 64x128: 1536 blocks (6/CU), 24 KB LDS, lower VGPR —
// targets the R3-measured latency/occupancy bound (MfmaUtil 18%, Occ 16%).
// Per-element accumulation order unchanged -> bit-identical q/k/v.
// XOR-swizzled LDS chunks; global_load_lds dest stays lane*16 contiguous.
// ---------------------------------------------------------------------------
__global__ __launch_bounds__(256) void gemm_qkv(
    const ushort_t* __restrict__ Aqh, const ushort_t* __restrict__ Aql,
    const ushort_t* __restrict__ Akh, const ushort_t* __restrict__ Akl,
    const ushort_t* __restrict__ Avh,
    const ushort_t* __restrict__ Wqh, const ushort_t* __restrict__ Wql,
    const ushort_t* __restrict__ Wkh, const ushort_t* __restrict__ Wkl,
    const ushort_t* __restrict__ Wvh,
    const float* __restrict__ bq, const float* __restrict__ bk,
    const float* __restrict__ bv,
    float* __restrict__ qo, float* __restrict__ ko, float* __restrict__ vo) {
  __shared__ ushort_t Ash[64][32], Asl[64][32];    // 4 KB each
  __shared__ ushort_t Bsh[128][32], Bsl[128][32];  // 8 KB each
  int which = blockIdx.z;
  const ushort_t* Ah = which == 0 ? Aqh : (which == 1 ? Akh : Avh);
  const ushort_t* Al = which == 0 ? Aql : Akl;  // unused for V
  const ushort_t* Bh = which == 0 ? Wqh : (which == 1 ? Wkh : Wvh);
  const ushort_t* Bl = which == 0 ? Wql : Wkl;
  const float* bias = which == 0 ? bq : (which == 1 ? bk : bv);
  float* C = which == 0 ? qo : (which == 1 ? ko : vo);
  const bool split = which < 2;

  int bm = blockIdx.x, bn = blockIdx.y;
  int tid = threadIdx.x;
  int wave = tid >> 6, lane = tid & 63;
  int wm = (wave & 1) * 32, wn = (wave >> 1) * 64;
  int quad = lane >> 4, lm = lane & 15;
  int srow = tid >> 2;                                  // staging row 0..63
  int slc = (((tid & 3) ^ ((tid >> 3) & 3))) * 8;       // logical chunk (global src)
  int sphys = (tid & 3) * 8;                            // physical chunk (LDS dest)
  int rsw = (quad ^ ((lm >> 1) & 3)) * 8;               // fragment read chunk
  facc4 acc[2][4] = {};

  for (int k0 = 0; k0 < 512; k0 += 32) {
    {
      size_t ga = (size_t)(bm * 64 + srow) * 512 + k0 + slc;
      gl2lds16(&Ah[ga], &Ash[srow][sphys]);
      if (split) gl2lds16(&Al[ga], &Asl[srow][sphys]);
    }
#pragma unroll
    for (int p = 0; p < 2; ++p) {
      int row = srow + p * 64;
      size_t gb = (size_t)(bn * 128 + row) * 512 + k0 + slc;
      gl2lds16(&Bh[gb], &Bsh[row][sphys]);
      if (split) gl2lds16(&Bl[gb], &Bsl[row][sphys]);
    }
    __syncthreads();
    bfrag8 afh[2], afl[2], bfh[4], bfl[4];
#pragma unroll
    for (int mt = 0; mt < 2; ++mt) {
      afh[mt] = *(bfrag8*)&Ash[wm + mt * 16 + lm][rsw];
      if (split) afl[mt] = *(bfrag8*)&Asl[wm + mt * 16 + lm][rsw];
    }
#pragma unroll
    for (int nt = 0; nt < 4; ++nt) {
      bfh[nt] = *(bfrag8*)&Bsh[wn + nt * 16 + lm][rsw];
      if (split) bfl[nt] = *(bfrag8*)&Bsl[wn + nt * 16 + lm][rsw];
    }
#pragma unroll
    for (int mt = 0; mt < 2; ++mt)
#pragma unroll
      for (int nt = 0; nt < 4; ++nt) {
        facc4 a = acc[mt][nt];
        a = __builtin_amdgcn_mfma_f32_16x16x32_bf16(afh[mt], bfh[nt], a, 0, 0, 0);
        if (split) {
          a = __builtin_amdgcn_mfma_f32_16x16x32_bf16(afl[mt], bfh[nt], a, 0, 0, 0);
          a = __builtin_amdgcn_mfma_f32_16x16x32_bf16(afh[mt], bfl[nt], a, 0, 0, 0);
        }
        acc[mt][nt] = a;
      }
    __syncthreads();
  }
#pragma unroll
  for (int mt = 0; mt < 2; ++mt)
#pragma unroll
    for (int nt = 0; nt < 4; ++nt) {
      int col = bn * 128 + wn + nt * 16 + lm;
      float bv2 = bias[col];
#pragma unroll
      for (int r = 0; r < 4; ++r) {
        int row = bm * 64 + wm + mt * 16 + quad * 4 + r;
        C[(size_t)row * 512 + col] = acc[mt][nt][r] + bv2;
      }
    }
}

// ---------------------------------------------------------------------------
// bf16 MFMA GEMM (hi only): out projection, 128x128 tile, swizzled LDS
// ---------------------------------------------------------------------------
__global__ __launch_bounds__(256) void gemm_bf16(
    const ushort_t* __restrict__ A, const ushort_t* __restrict__ Bt,
    const float* __restrict__ bias, float* __restrict__ C) {
  __shared__ ushort_t As[128][32];
  __shared__ ushort_t Bs[128][32];
  int bm = blockIdx.x, bn = blockIdx.y;
  int tid = threadIdx.x;
  int wave = tid >> 6, lane = tid & 63;
  int wm = (wave & 1) * 64, wn = (wave >> 1) * 64;
  int quad = lane >> 4, lm = lane & 15;
  int srow = tid >> 2;
  int slc = (((tid & 3) ^ ((tid >> 3) & 3))) * 8;
  int sphys = (tid & 3) * 8;
  int rsw = (quad ^ ((lm >> 1) & 3)) * 8;
  facc4 acc[4][4] = {};

  for (int k0 = 0; k0 < 512; k0 += 32) {
#pragma unroll
    for (int p = 0; p < 2; ++p) {
      int row = srow + p * 64;
      gl2lds16(&A[(size_t)(bm * 128 + row) * 512 + k0 + slc], &As[row][sphys]);
      gl2lds16(&Bt[(size_t)(bn * 128 + row) * 512 + k0 + slc], &Bs[row][sphys]);
    }
    __syncthreads();
    bfrag8 af[4], bf[4];
#pragma unroll
    for (int mt = 0; mt < 4; ++mt)
      af[mt] = *(bfrag8*)&As[wm + mt * 16 + lm][rsw];
#pragma unroll
    for (int nt = 0; nt < 4; ++nt)
      bf[nt] = *(bfrag8*)&Bs[wn + nt * 16 + lm][rsw];
#pragma unroll
    for (int mt = 0; mt < 4; ++mt)
#pragma unroll
      for (int nt = 0; nt < 4; ++nt)
        acc[mt][nt] = __builtin_amdgcn_mfma_f32_16x16x32_bf16(
            af[mt], bf[nt], acc[mt][nt], 0, 0, 0);
    __syncthreads();
  }
#pragma unroll
  for (int mt = 0; mt < 4; ++mt)
#pragma unroll
    for (int nt = 0; nt < 4; ++nt) {
      int col = bn * 128 + wn + nt * 16 + lm;
      float bv = bias[col];
#pragma unroll
      for (int r = 0; r < 4; ++r) {
        int row = bm * 128 + wm + mt * 16 + quad * 4 + r;
        C[(size_t)row * 512 + col] = acc[mt][nt][r] + bv;
      }
    }
}

// ---------------------------------------------------------------------------
// Fused: blocks <4096 = compute_m; blocks >=4096 = tile_sum (2 tiles/block).
// m[b,h,l] = max_s(q.k_sample) - sum_s(q.k_sample)/L  (bit-exact selection)
// ---------------------------------------------------------------------------
__global__ __launch_bounds__(256) void compute_m_tiles(
    const float* __restrict__ q, const float* __restrict__ k,
    const int* __restrict__ idxs, float* __restrict__ m,
    const float* __restrict__ v, float* __restrict__ tsum) {
  int bx = blockIdx.x;
  if (bx >= 4096) {
    // tile_sum: 512 units, 2 per block
    int unit = (bx - 4096) * 2 + (threadIdx.x >> 7);
    int d4 = threadIdx.x & 127;
    int tile = unit & (NTILE - 1);
    int b = unit >> 7;
    float4 s = {0.f, 0.f, 0.f, 0.f};
    const float* base = &v[((size_t)b * Lq + tile * TSCAN) * Dq + d4 * 4];
#pragma unroll
    for (int r = 0; r < TSCAN; ++r) {
      float4 x = *(const float4*)&base[(size_t)r * Dq];
      s.x += x.x; s.y += x.y; s.z += x.z; s.w += x.w;
    }
    *(float4*)&tsum[((size_t)b * NTILE + tile) * Dq + d4 * 4] = s;
    return;
  }
  int wave = threadIdx.x >> 6, lane = threadIdx.x & 63;
  int lq = lane >> 4, dq = lane & 15;
  int slot = (bx * 4 + wave) * 4 + lq;  // (b,h,l) flat
  int l = slot & (Lq - 1);
  int bh = slot >> 11;
  int h = bh & (Hq - 1), b = bh >> 3;
  float4 qv = *(const float4*)&q[((size_t)b * Lq + l) * Dq + h * DKq + dq * 4];
  const float* kb = &k[(size_t)b * Lq * Dq + h * DKq + dq * 4];
  const int* ib = &idxs[l * Uq];
  float mx = -INFINITY, sm = 0.f;
#pragma unroll
  for (int s = 0; s < Uq; ++s) {
    int j = ib[s];
    float4 kv = *(const float4*)&kb[(size_t)j * Dq];
    float p = qv.x * kv.x + qv.y * kv.y + qv.z * kv.z + qv.w * kv.w;
    p += __shfl_xor(p, 1, 64);
    p += __shfl_xor(p, 2, 64);
    p += __shfl_xor(p, 4, 64);
    p += __shfl_xor(p, 8, 64);
    mx = fmaxf(mx, p);
    sm += p;
  }
  if (dq == 0) m[slot] = mx - sm * (1.0f / Lq);
}

// ---------------------------------------------------------------------------
// Fused: blocks <32 = top-24 per (b,h) (24-round argmax, builds repl);
// blocks 32..63 = stile_sum (2 supertile units/block).
// Selection bit-identical to two-stage bitonic: key=(fkey(v)<<32)|(L-1-idx).
// ---------------------------------------------------------------------------
__global__ __launch_bounds__(256) void topk_stile(
    const float* __restrict__ m, int* __restrict__ mtop,
    int* __restrict__ repl, const float* __restrict__ tsum,
    float* __restrict__ stsum) {
  if (blockIdx.x >= 32) {
    int unit = (blockIdx.x - 32) * 2 + (threadIdx.x >> 7);  // 0..63
    int d4 = threadIdx.x & 127;
    int s = unit & (NSUP - 1);
    int b = unit >> 4;
    float4 acc = {0.f, 0.f, 0.f, 0.f};
    const float* tb = &tsum[((size_t)b * NTILE + s * 8) * Dq + d4 * 4];
#pragma unroll
    for (int i = 0; i < 8; ++i) {
      float4 t = *(const float4*)&tb[(size_t)i * Dq];
      acc.x += t.x; acc.y += t.y; acc.z += t.z; acc.w += t.w;
    }
    *(float4*)&stsum[((size_t)b * NSUP + s) * Dq + d4 * 4] = acc;
    return;
  }
  __shared__ u64 red[2][4];
  __shared__ int mt[Uq];
  int bh = blockIdx.x;
  int tid = threadIdx.x, wave = tid >> 6, lane = tid & 63;
  u64 keys[TKCH];
#pragma unroll
  for (int c = 0; c < TKCH; ++c) {
    int gidx = c * 256 + tid;
    float v = m[(size_t)bh * Lq + gidx];
    keys[c] = ((u64)fkey(v) << 32) | (u64)(Lq - 1 - gidx);
  }
#pragma unroll 1
  for (int it = 0; it < Uq; ++it) {
    u64 lb = keys[0];
#pragma unroll
    for (int c = 1; c < TKCH; ++c) lb = keys[c] > lb ? keys[c] : lb;
#pragma unroll
    for (int off = 32; off; off >>= 1) {
      u64 o = __shfl_xor(lb, off, 64);
      lb = o > lb ? o : lb;
    }
    int p = it & 1;
    if (lane == 0) red[p][wave] = lb;
    __syncthreads();
    u64 w0 = red[p][0] > red[p][1] ? red[p][0] : red[p][1];
    u64 w1 = red[p][2] > red[p][3] ? red[p][2] : red[p][3];
    u64 win = w0 > w1 ? w0 : w1;
    if (tid == 0) {
      int idx = Lq - 1 - (int)(win & 0xFFFFFFFFull);
      mtop[bh * Uq + it] = idx;
      mt[it] = idx;
    }
#pragma unroll
    for (int c = 0; c < TKCH; ++c)
      if (keys[c] == win) keys[c] = 0;
  }
  __syncthreads();
  int* rb = &repl[(size_t)bh * Lq];
#pragma unroll
  for (int c = 0; c < TKCH; ++c) rb[c * 256 + tid] = -1;
  __syncthreads();
  if (tid < Uq) rb[mt[tid]] = tid;
}

// ---------------------------------------------------------------------------
// FUSED attention on top-24 rows: scores + chunk softmax + PV partials.
// One block per (bh, jt=128-j chunk) -> 512 blocks (2/CU). Scores stay
// bit-identical (same per-thread fp32 FMA order). V tile staged once per
// chunk, reused across all 24 u.
// ---------------------------------------------------------------------------
#define JS 64

__global__ __launch_bounds__(256) void attn_fused(
    const float* __restrict__ q, const float* __restrict__ k,
    const float* __restrict__ v, const int* __restrict__ mtop,
    float* __restrict__ pmax, float* __restrict__ psum,
    float* __restrict__ pvp) {
  __shared__ float qs[Uq][DKq + 1];   // 6.2 KB
  __shared__ float ks[JS][DKq + 1];   // 16.6 KB (reused as V tile in PV)
  __shared__ float es[Uq][132];       // 12.7 KB (132*4B: float4-aligned rows)
  __shared__ int i0s[Uq];
  int jt = blockIdx.x;   // 0..15
  int bh = blockIdx.y;   // 0..31
  int h = bh & (Hq - 1);
  int b = bh >> 3;
  int tid = threadIdx.x;
  if (tid < Uq) i0s[tid] = mtop[bh * Uq + tid];
  __syncthreads();
  int maxn = 0;
#pragma unroll
  for (int u2 = 0; u2 < Uq; ++u2) maxn = max(maxn, i0s[u2] + 1);
  int jbase0 = jt * JCH;
  if (maxn <= jbase0) return;  // uniform: no u needs this chunk

  // stage q rows (24 x 64)
  for (int s = tid; s < Uq * 16; s += 256) {
    int u = s >> 4, qd = (s & 15) * 4;
    float4 t = *(const float4*)&q[((size_t)b * Lq + i0s[u]) * Dq + h * DKq + qd];
    qs[u][qd] = t.x; qs[u][qd + 1] = t.y; qs[u][qd + 2] = t.z; qs[u][qd + 3] = t.w;
  }
  int jp = tid & 31;
  int ug = tid >> 5;
  float sreg[3][4] = {};  // [uu][sub*2 + jj]
#pragma unroll
  for (int sub = 0; sub < 2; ++sub) {
    int jb = jbase0 + sub * JS;
    __syncthreads();
    if (jb < maxn) {
      for (int s = tid; s < JS * 16; s += 256) {
        int j = s >> 4, qd = (s & 15) * 4;
        float4 t =
            *(const float4*)&k[((size_t)b * Lq + jb + j) * Dq + h * DKq + qd];
        ks[j][qd] = t.x; ks[j][qd + 1] = t.y;
        ks[j][qd + 2] = t.z; ks[j][qd + 3] = t.w;
      }
    }
    __syncthreads();
    if (jb < maxn) {
      float acc[3][2] = {};
      int j0 = jp * 2, j1 = j0 + 1;
#pragma unroll 8
      for (int d = 0; d < DKq; ++d) {
        float k0 = ks[j0][d], k1 = ks[j1][d];
#pragma unroll
        for (int uu = 0; uu < 3; ++uu) {
          float qv = qs[ug * 3 + uu][d];
          acc[uu][0] += qv * k0;
          acc[uu][1] += qv * k1;
        }
      }
#pragma unroll
      for (int uu = 0; uu < 3; ++uu) {
        sreg[uu][sub * 2] = acc[uu][0];
        sreg[uu][sub * 2 + 1] = acc[uu][1];
      }
    }
  }

  // per-u chunk softmax (32-lane groups; lanes of group share ug)
  const float scale = 0.044194173824159216f;  // 1/sqrt(512)
#pragma unroll
  for (int uu = 0; uu < 3; ++uu) {
    int u = ug * 3 + uu;
    int lu = i0s[u];
    float sv[4];
    float mx = -INFINITY;
#pragma unroll
    for (int t = 0; t < 4; ++t) {
      int jl = (t >> 1) * JS + jp * 2 + (t & 1);
      float x = sreg[uu][t] * scale;
      bool ok = (jbase0 + jl) <= lu;  // causal: j < n
      x = ok ? x : -INFINITY;
      sv[t] = x;
      mx = fmaxf(mx, x);
    }
#pragma unroll
    for (int off = 16; off; off >>= 1) mx = fmaxf(mx, __shfl_xor(mx, off, 64));
    float sm = 0.f;
#pragma unroll
    for (int t = 0; t < 4; ++t) {
      int jl = (t >> 1) * JS + jp * 2 + (t & 1);
      float e = (sv[t] == -INFINITY) ? 0.f : __expf(sv[t] - mx);
      es[u][jl] = e;
      sm += e;
    }
#pragma unroll
    for (int off = 16; off; off >>= 1) sm += __shfl_xor(sm, off, 64);
    if (jp == 0) {
      int blku = bh * Uq + u;
      pmax[blku * NCH + jt] = mx;   // garbage(-inf) chunks are never read
      psum[blku * NCH + jt] = sm;
    }
  }

  // PV: stage V sub-tile once, reuse across all 24 u. wave w owns u=w*6..+5
  int wv = tid >> 6, lane = tid & 63;
  float a6[6] = {};
#pragma unroll
  for (int sub = 0; sub < 2; ++sub) {
    int jb = jbase0 + sub * JS;
    __syncthreads();  // prev sub's reads done (and es complete before sub 0)
    if (jb < maxn) {
      for (int s = tid; s < JS * 16; s += 256) {
        int j = s >> 4, qd = (s & 15) * 4;
        float4 t =
            *(const float4*)&v[((size_t)b * Lq + jb + j) * Dq + h * DKq + qd];
        ks[j][qd] = t.x; ks[j][qd + 1] = t.y;
        ks[j][qd + 2] = t.z; ks[j][qd + 3] = t.w;
      }
    }
    __syncthreads();
    if (jb < maxn) {
#pragma unroll 4
      for (int j = 0; j < JS; j += 4) {
        float v0 = ks[j][lane], v1 = ks[j + 1][lane];
        float v2 = ks[j + 2][lane], v3 = ks[j + 3][lane];
#pragma unroll
        for (int uu = 0; uu < 6; ++uu) {
          float4 ee = *(const float4*)&es[wv * 6 + uu][sub * JS + j];
          a6[uu] += ee.x * v0 + ee.y * v1 + ee.z * v2 + ee.w * v3;
        }
      }
    }
  }
#pragma unroll
  for (int uu = 0; uu < 6; ++uu) {
    int blku = bh * Uq + wv * 6 + uu;
    pvp[((size_t)blku * NCH + jt) * DKq + lane] = a6[uu];
  }
}

// ---------------------------------------------------------------------------
// build_context: two-level exclusive prefix (<=22 loads), inline softmax
// combine at replaced rows, bf16 out.
// ---------------------------------------------------------------------------
__global__ __launch_bounds__(128) void build_context(
    const float* __restrict__ v, const float* __restrict__ tsum,
    const float* __restrict__ stsum, const int* __restrict__ repl,
    const float* __restrict__ pmax, const float* __restrict__ psum,
    const float* __restrict__ pvp, ushort_t* __restrict__ ctxh) {
  int blk = blockIdx.x;  // b*NTILE + tile
  int tile = blk & (NTILE - 1);
  int b = blk >> 7;
  int d4 = threadIdx.x;          // float4 column slice
  int h = d4 >> 4;               // (d4*4)>>6
  int sup = tile >> 3;
  float4 run = {0.f, 0.f, 0.f, 0.f};
  const float* sb = &stsum[(size_t)b * NSUP * Dq + d4 * 4];
  for (int s = 0; s < sup; ++s) {
    float4 t = *(const float4*)&sb[(size_t)s * Dq];
    run.x += t.x; run.y += t.y; run.z += t.z; run.w += t.w;
  }
  const float* tb = &tsum[((size_t)b * NTILE + sup * 8) * Dq + d4 * 4];
  int rem = tile & 7;
  for (int i = 0; i < rem; ++i) {
    float4 t = *(const float4*)&tb[(size_t)i * Dq];
    run.x += t.x; run.y += t.y; run.z += t.z; run.w += t.w;
  }
  const int* replb = &repl[(size_t)(b * Hq + h) * Lq + tile * TSCAN];
  const float* vb = &v[((size_t)b * Lq + tile * TSCAN) * Dq + d4 * 4];
  ushort_t* cb = &ctxh[((size_t)b * Lq + tile * TSCAN) * Dq + d4 * 4];
#pragma unroll
  for (int r = 0; r < TSCAN; ++r) {
    float4 x = *(const float4*)&vb[(size_t)r * Dq];
    run.x += x.x; run.y += x.y; run.z += x.z; run.w += x.w;
    int u = replb[r];
    float4 val = run;
    if (u >= 0) {
      // inline softmax combine: l == mtop[u]  =>  n = l+1
      int l = tile * TSCAN + r;
      int blku = (b * Hq + h) * Uq + u;
      int nc = (l + JCH) / JCH;  // ceil((l+1)/JCH)
      float gmax = -INFINITY;
      for (int c = 0; c < nc; ++c) gmax = fmaxf(gmax, pmax[blku * NCH + c]);
      float tot = 0.f;
      float4 acc = {0.f, 0.f, 0.f, 0.f};
      for (int c = 0; c < nc; ++c) {
        float wgt = __expf(pmax[blku * NCH + c] - gmax);
        tot += psum[blku * NCH + c] * wgt;
        float4 pv = *(const float4*)&pvp[((size_t)blku * NCH + c) * DKq +
                                         (d4 & 15) * 4];
        acc.x += pv.x * wgt; acc.y += pv.y * wgt;
        acc.z += pv.z * wgt; acc.w += pv.w * wgt;
      }
      float inv = 1.0f / tot;
      val.x = acc.x * inv; val.y = acc.y * inv;
      val.z = acc.z * inv; val.w = acc.w * inv;
    }
    ushort4 o = {bf16_rne(val.x), bf16_rne(val.y), bf16_rne(val.z),
                 bf16_rne(val.w)};
    *(ushort4*)&cb[(size_t)r * Dq] = o;
  }
}

// ---------------------------------------------------------------------------
extern "C" void kernel_launch(void* const* d_in, const int* in_sizes, int n_in,
                              void* d_out, int out_size, void* d_ws,
                              size_t ws_size, hipStream_t stream) {
  const float* queries = (const float*)d_in[0];
  const float* keys    = (const float*)d_in[1];
  const float* values  = (const float*)d_in[2];
  const int*   idxs    = (const int*)d_in[3];
  const float* Wq = (const float*)d_in[4];
  const float* bq = (const float*)d_in[5];
  const float* Wk = (const float*)d_in[6];
  const float* bk = (const float*)d_in[7];
  const float* Wv = (const float*)d_in[8];
  const float* bv = (const float*)d_in[9];
  const float* Wo = (const float*)d_in[10];
  const float* bo = (const float*)d_in[11];
  float* out = (float*)d_out;

  const size_t BLD = (size_t)Bq * Lq * Dq;  // 4,194,304
  char* w = (char*)d_ws;
  float* q    = (float*)w; w += BLD * 4;
  float* k    = (float*)w; w += BLD * 4;
  float* v    = (float*)w; w += BLD * 4;
  float* m    = (float*)w; w += (size_t)Bq * Hq * Lq * 4;
  float* tsum = (float*)w; w += (size_t)Bq * NTILE * Dq * 4;
  float* stsum= (float*)w; w += (size_t)Bq * NSUP * Dq * 4;
  int* mtop   = (int*)w;   w += Bq * Hq * Uq * 4;
  int* repl   = (int*)w;   w += (size_t)Bq * Hq * Lq * 4;
  float* pmax = (float*)w; w += (size_t)Bq * Hq * Uq * NCH * 4;
  float* psum = (float*)w; w += (size_t)Bq * Hq * Uq * NCH * 4;
  float* pvp  = (float*)w; w += (size_t)Bq * Hq * Uq * NCH * DKq * 4;
  ushort_t* ctxh = (ushort_t*)w; w += BLD * 2;  // bf16 context
  ushort_t* Aqh = (ushort_t*)w; w += BLD * 2;   // pre-cast activations
  ushort_t* Aql = (ushort_t*)w; w += BLD * 2;
  ushort_t* Akh = (ushort_t*)w; w += BLD * 2;
  ushort_t* Akl = (ushort_t*)w; w += BLD * 2;
  ushort_t* Avh = (ushort_t*)w; w += BLD * 2;
  const size_t WSZ = 512 * 512;
  ushort_t* Wqh = (ushort_t*)w; w += WSZ * 2;
  ushort_t* Wql = (ushort_t*)w; w += WSZ * 2;
  ushort_t* Wkh = (ushort_t*)w; w += WSZ * 2;
  ushort_t* Wkl = (ushort_t*)w; w += WSZ * 2;
  ushort_t* Wvh = (ushort_t*)w; w += WSZ * 2;
  ushort_t* Woh = (ushort_t*)w; w += WSZ * 2;

  // all input prep (activation casts + weight transpose/cast), ONE launch
  {
    dim3 pgrid(BLD / 4 / 256, 4);  // (4096, 4); y==3 uses first 1024 blocks
    prep_all<<<pgrid, 256, 0, stream>>>(queries, keys, values, Aqh, Aql, Akh,
                                        Akl, Avh, Wq, Wk, Wv, Wo, Wqh, Wql,
                                        Wkh, Wkl, Wvh, Woh);
  }

  // fused Q/K/V projections (64x128 tiles, 1536 blocks = 6/CU)
  {
    dim3 ggrid(128, 4, 3);  // M=8192/64, N=512/128, z = Q/K/V
    gemm_qkv<<<ggrid, 256, 0, stream>>>(Aqh, Aql, Akh, Akl, Avh, Wqh, Wql,
                                        Wkh, Wkl, Wvh, bq, bk, bv, q, k, v);
  }

  // sparsity metric + v tile sums (independent, one launch)
  compute_m_tiles<<<4096 + 256, 256, 0, stream>>>(q, k, idxs, m, v, tsum);

  // fused top-k (builds repl) + supertile sums (independent, one launch)
  topk_stile<<<64, 256, 0, stream>>>(m, mtop, repl, tsum, stsum);

  // fused scores + softmax + PV partials (128-j chunks, 512 blocks)
  {
    dim3 agrid(Lq / JCH, Bq * Hq);  // (16, 32)
    attn_fused<<<agrid, 256, 0, stream>>>(q, k, v, mtop, pmax, psum, pvp);
  }

  // cumsum context with two-level prefix + inline combine
  build_context<<<Bq * NTILE, 128, 0, stream>>>(v, tsum, stsum, repl, pmax,
                                                psum, pvp, ctxh);

  // output projection (plain bf16, 128x128 tiles, swizzled LDS)
  {
    dim3 ggrid(64, 4);
    gemm_bf16<<<ggrid, 256, 0, stream>>>(ctxh, Woh, bo, out);
  }
}

// Round 6
// 262.595 us; speedup vs baseline: 1.0094x; 1.0094x over previous
//
#include <hip/hip_runtime.h>
#include <hip/hip_bf16.h>
#include <math.h>

#define Bq 4
#define Lq 2048
#define Dq 512
#define Hq 8
#define DKq 64
#define Uq 24
#define TSCAN 16
#define NTILE (Lq / TSCAN)   // 128
#define NSUP 16              // supertiles (8 tiles each)
#define JCH 128              // softmax j-chunk
#define NCH (Lq / JCH)       // 16
#define TKCH 8               // m-chunks per thread in topk (2048/256)

typedef unsigned short ushort_t;
typedef unsigned long long u64;
typedef __attribute__((ext_vector_type(8))) short bfrag8;   // 8 bf16 (4 VGPRs)
typedef __attribute__((ext_vector_type(4))) float facc4;    // MFMA accumulator

__device__ inline ushort_t bf16_rne(float f) {
  unsigned u = __float_as_uint(f);
  u += 0x7FFF + ((u >> 16) & 1);
  return (ushort_t)(u >> 16);
}
__device__ inline float bf16f(ushort_t h) {
  return __uint_as_float(((unsigned)h) << 16);
}
// monotone float -> uint map (no NaNs in inputs)
__device__ inline unsigned fkey(float f) {
  unsigned u = __float_as_uint(f);
  return (u & 0x80000000u) ? ~u : (u | 0x80000000u);
}
// async global->LDS, 16B per lane (lds dest = wave base + lane*16)
__device__ __forceinline__ void gl2lds16(const void* g, void* l) {
  __builtin_amdgcn_global_load_lds(
      (const __attribute__((address_space(1))) unsigned*)g,
      (__attribute__((address_space(3))) unsigned*)l, 16, 0, 0);
}

// ---------------------------------------------------------------------------
// prep_w: weights only — fp32 [k][n] -> transposed bf16 hi/lo [n][k].
// (Activation casts are now fused into gemm_qkv's A-staging.)
// ---------------------------------------------------------------------------
__global__ __launch_bounds__(256) void prep_w(
    const float* __restrict__ W0, const float* __restrict__ W1,
    const float* __restrict__ W2, const float* __restrict__ W3,
    ushort_t* __restrict__ T0h, ushort_t* __restrict__ T0l,
    ushort_t* __restrict__ T1h, ushort_t* __restrict__ T1l,
    ushort_t* __restrict__ T2h, ushort_t* __restrict__ T3h) {
  __shared__ float tile[32][33];
  int z = blockIdx.z;
  const float* W = z == 0 ? W0 : (z == 1 ? W1 : (z == 2 ? W2 : W3));
  ushort_t* Th = z == 0 ? T0h : (z == 1 ? T1h : (z == 2 ? T2h : T3h));
  ushort_t* Tl = z == 0 ? T0l : (z == 1 ? T1l : nullptr);
  int k0 = blockIdx.x * 32, n0 = blockIdx.y * 32;
  int tx = threadIdx.x & 31, ty = threadIdx.x >> 5;  // ty 0..7
  for (int r = ty; r < 32; r += 8)
    tile[tx][r] = W[(size_t)(k0 + r) * 512 + n0 + tx];
  __syncthreads();
  for (int r = ty; r < 32; r += 8) {
    float v = tile[r][tx];
    ushort_t h = bf16_rne(v);
    Th[(size_t)(n0 + r) * 512 + k0 + tx] = h;
    if (Tl) Tl[(size_t)(n0 + r) * 512 + k0 + tx] = bf16_rne(v - bf16f(h));
  }
}

// ---------------------------------------------------------------------------
// Fused Q/K/V projection GEMM, 128x128 tile, 4 waves x (64x64).
// z=0: Q (split-bf16), z=1: K (split), z=2: V (plain hi).
// A is read as RAW FP32 activations and split-cast in-register during
// staging (bit-identical formula to the old prep_all pass -> bit-identical
// q/k/v). Same staged bytes/K-step (8 fp32 = 16B hi + 16B lo). B stays
// global_load_lds from pre-transposed bf16 weights.
// XOR-swizzled LDS chunks; B's LDS dest stays lane*16 contiguous.
// ---------------------------------------------------------------------------
__global__ __launch_bounds__(256) void gemm_qkv(
    const float* __restrict__ xq, const float* __restrict__ xk,
    const float* __restrict__ xv,
    const ushort_t* __restrict__ Wqh, const ushort_t* __restrict__ Wql,
    const ushort_t* __restrict__ Wkh, const ushort_t* __restrict__ Wkl,
    const ushort_t* __restrict__ Wvh,
    const float* __restrict__ bq, const float* __restrict__ bk,
    const float* __restrict__ bv,
    float* __restrict__ qo, float* __restrict__ ko, float* __restrict__ vo) {
  __shared__ ushort_t Ash[128][32], Asl[128][32];  // 8 KB each
  __shared__ ushort_t Bsh[128][32], Bsl[128][32];
  int which = blockIdx.z;
  const float* Af = which == 0 ? xq : (which == 1 ? xk : xv);
  const ushort_t* Bh = which == 0 ? Wqh : (which == 1 ? Wkh : Wvh);
  const ushort_t* Bl = which == 0 ? Wql : Wkl;
  const float* bias = which == 0 ? bq : (which == 1 ? bk : bv);
  float* C = which == 0 ? qo : (which == 1 ? ko : vo);
  const bool split = which < 2;

  int bm = blockIdx.x, bn = blockIdx.y;
  int tid = threadIdx.x;
  int wave = tid >> 6, lane = tid & 63;
  int wm = (wave & 1) * 64, wn = (wave >> 1) * 64;
  int quad = lane >> 4, lm = lane & 15;
  int srow = tid >> 2;                                  // staging row (p=0)
  int slc = (((tid & 3) ^ ((tid >> 3) & 3))) * 8;       // logical chunk (global src)
  int sphys = (tid & 3) * 8;                            // physical chunk (LDS dest)
  int rsw = (quad ^ ((lm >> 1) & 3)) * 8;               // fragment read chunk
  facc4 acc[4][4] = {};

  for (int k0 = 0; k0 < 512; k0 += 32) {
    // B: async direct global->LDS (bf16 pre-cast weights)
#pragma unroll
    for (int p = 0; p < 2; ++p) {
      int row = srow + p * 64;
      size_t gb = (size_t)(bn * 128 + row) * 512 + k0 + slc;
      gl2lds16(&Bh[gb], &Bsh[row][sphys]);
      if (split) gl2lds16(&Bl[gb], &Bsl[row][sphys]);
    }
    // A: fp32 load + in-register split cast + ds_write (fused prep)
#pragma unroll
    for (int p = 0; p < 2; ++p) {
      int row = srow + p * 64;
      const float* ga = &Af[(size_t)(bm * 128 + row) * 512 + k0 + slc];
      float4 a0 = *(const float4*)ga;
      float4 a1 = *(const float4*)(ga + 4);
      bfrag8 hv, lv;
      {
        float f0 = a0.x, f1 = a0.y, f2 = a0.z, f3 = a0.w;
        float f4 = a1.x, f5 = a1.y, f6 = a1.z, f7 = a1.w;
        ushort_t h0 = bf16_rne(f0), h1 = bf16_rne(f1), h2 = bf16_rne(f2),
                 h3 = bf16_rne(f3), h4 = bf16_rne(f4), h5 = bf16_rne(f5),
                 h6 = bf16_rne(f6), h7 = bf16_rne(f7);
        hv[0] = (short)h0; hv[1] = (short)h1; hv[2] = (short)h2;
        hv[3] = (short)h3; hv[4] = (short)h4; hv[5] = (short)h5;
        hv[6] = (short)h6; hv[7] = (short)h7;
        if (split) {
          lv[0] = (short)bf16_rne(f0 - bf16f(h0));
          lv[1] = (short)bf16_rne(f1 - bf16f(h1));
          lv[2] = (short)bf16_rne(f2 - bf16f(h2));
          lv[3] = (short)bf16_rne(f3 - bf16f(h3));
          lv[4] = (short)bf16_rne(f4 - bf16f(h4));
          lv[5] = (short)bf16_rne(f5 - bf16f(h5));
          lv[6] = (short)bf16_rne(f6 - bf16f(h6));
          lv[7] = (short)bf16_rne(f7 - bf16f(h7));
        }
      }
      *(bfrag8*)&Ash[row][sphys] = hv;
      if (split) *(bfrag8*)&Asl[row][sphys] = lv;
    }
    __syncthreads();
    bfrag8 afh[4], afl[4], bfh[4], bfl[4];
#pragma unroll
    for (int mt = 0; mt < 4; ++mt) {
      afh[mt] = *(bfrag8*)&Ash[wm + mt * 16 + lm][rsw];
      if (split) afl[mt] = *(bfrag8*)&Asl[wm + mt * 16 + lm][rsw];
    }
#pragma unroll
    for (int nt = 0; nt < 4; ++nt) {
      bfh[nt] = *(bfrag8*)&Bsh[wn + nt * 16 + lm][rsw];
      if (split) bfl[nt] = *(bfrag8*)&Bsl[wn + nt * 16 + lm][rsw];
    }
#pragma unroll
    for (int mt = 0; mt < 4; ++mt)
#pragma unroll
      for (int nt = 0; nt < 4; ++nt) {
        facc4 a = acc[mt][nt];
        a = __builtin_amdgcn_mfma_f32_16x16x32_bf16(afh[mt], bfh[nt], a, 0, 0, 0);
        if (split) {
          a = __builtin_amdgcn_mfma_f32_16x16x32_bf16(afl[mt], bfh[nt], a, 0, 0, 0);
          a = __builtin_amdgcn_mfma_f32_16x16x32_bf16(afh[mt], bfl[nt], a, 0, 0, 0);
        }
        acc[mt][nt] = a;
      }
    __syncthreads();
  }
#pragma unroll
  for (int mt = 0; mt < 4; ++mt)
#pragma unroll
    for (int nt = 0; nt < 4; ++nt) {
      int col = bn * 128 + wn + nt * 16 + lm;
      float bv2 = bias[col];
#pragma unroll
      for (int r = 0; r < 4; ++r) {
        int row = bm * 128 + wm + mt * 16 + quad * 4 + r;
        C[(size_t)row * 512 + col] = acc[mt][nt][r] + bv2;
      }
    }
}

// ---------------------------------------------------------------------------
// bf16 MFMA GEMM (hi only): out projection, 128x128 tile, swizzled LDS
// ---------------------------------------------------------------------------
__global__ __launch_bounds__(256) void gemm_bf16(
    const ushort_t* __restrict__ A, const ushort_t* __restrict__ Bt,
    const float* __restrict__ bias, float* __restrict__ C) {
  __shared__ ushort_t As[128][32];
  __shared__ ushort_t Bs[128][32];
  int bm = blockIdx.x, bn = blockIdx.y;
  int tid = threadIdx.x;
  int wave = tid >> 6, lane = tid & 63;
  int wm = (wave & 1) * 64, wn = (wave >> 1) * 64;
  int quad = lane >> 4, lm = lane & 15;
  int srow = tid >> 2;
  int slc = (((tid & 3) ^ ((tid >> 3) & 3))) * 8;
  int sphys = (tid & 3) * 8;
  int rsw = (quad ^ ((lm >> 1) & 3)) * 8;
  facc4 acc[4][4] = {};

  for (int k0 = 0; k0 < 512; k0 += 32) {
#pragma unroll
    for (int p = 0; p < 2; ++p) {
      int row = srow + p * 64;
      gl2lds16(&A[(size_t)(bm * 128 + row) * 512 + k0 + slc], &As[row][sphys]);
      gl2lds16(&Bt[(size_t)(bn * 128 + row) * 512 + k0 + slc], &Bs[row][sphys]);
    }
    __syncthreads();
    bfrag8 af[4], bf[4];
#pragma unroll
    for (int mt = 0; mt < 4; ++mt)
      af[mt] = *(bfrag8*)&As[wm + mt * 16 + lm][rsw];
#pragma unroll
    for (int nt = 0; nt < 4; ++nt)
      bf[nt] = *(bfrag8*)&Bs[wn + nt * 16 + lm][rsw];
#pragma unroll
    for (int mt = 0; mt < 4; ++mt)
#pragma unroll
      for (int nt = 0; nt < 4; ++nt)
        acc[mt][nt] = __builtin_amdgcn_mfma_f32_16x16x32_bf16(
            af[mt], bf[nt], acc[mt][nt], 0, 0, 0);
    __syncthreads();
  }
#pragma unroll
  for (int mt = 0; mt < 4; ++mt)
#pragma unroll
    for (int nt = 0; nt < 4; ++nt) {
      int col = bn * 128 + wn + nt * 16 + lm;
      float bv = bias[col];
#pragma unroll
      for (int r = 0; r < 4; ++r) {
        int row = bm * 128 + wm + mt * 16 + quad * 4 + r;
        C[(size_t)row * 512 + col] = acc[mt][nt][r] + bv;
      }
    }
}

// ---------------------------------------------------------------------------
// Fused: blocks <4096 = compute_m; blocks >=4096 = tile_sum (2 tiles/block).
// m[b,h,l] = max_s(q.k_sample) - sum_s(q.k_sample)/L  (bit-exact selection)
// ---------------------------------------------------------------------------
__global__ __launch_bounds__(256) void compute_m_tiles(
    const float* __restrict__ q, const float* __restrict__ k,
    const int* __restrict__ idxs, float* __restrict__ m,
    const float* __restrict__ v, float* __restrict__ tsum) {
  int bx = blockIdx.x;
  if (bx >= 4096) {
    // tile_sum: 512 units, 2 per block
    int unit = (bx - 4096) * 2 + (threadIdx.x >> 7);
    int d4 = threadIdx.x & 127;
    int tile = unit & (NTILE - 1);
    int b = unit >> 7;
    float4 s = {0.f, 0.f, 0.f, 0.f};
    const float* base = &v[((size_t)b * Lq + tile * TSCAN) * Dq + d4 * 4];
#pragma unroll
    for (int r = 0; r < TSCAN; ++r) {
      float4 x = *(const float4*)&base[(size_t)r * Dq];
      s.x += x.x; s.y += x.y; s.z += x.z; s.w += x.w;
    }
    *(float4*)&tsum[((size_t)b * NTILE + tile) * Dq + d4 * 4] = s;
    return;
  }
  int wave = threadIdx.x >> 6, lane = threadIdx.x & 63;
  int lq = lane >> 4, dq = lane & 15;
  int slot = (bx * 4 + wave) * 4 + lq;  // (b,h,l) flat
  int l = slot & (Lq - 1);
  int bh = slot >> 11;
  int h = bh & (Hq - 1), b = bh >> 3;
  float4 qv = *(const float4*)&q[((size_t)b * Lq + l) * Dq + h * DKq + dq * 4];
  const float* kb = &k[(size_t)b * Lq * Dq + h * DKq + dq * 4];
  const int* ib = &idxs[l * Uq];
  float mx = -INFINITY, sm = 0.f;
#pragma unroll
  for (int s = 0; s < Uq; ++s) {
    int j = ib[s];
    float4 kv = *(const float4*)&kb[(size_t)j * Dq];
    float p = qv.x * kv.x + qv.y * kv.y + qv.z * kv.z + qv.w * kv.w;
    p += __shfl_xor(p, 1, 64);
    p += __shfl_xor(p, 2, 64);
    p += __shfl_xor(p, 4, 64);
    p += __shfl_xor(p, 8, 64);
    mx = fmaxf(mx, p);
    sm += p;
  }
  if (dq == 0) m[slot] = mx - sm * (1.0f / Lq);
}

// ---------------------------------------------------------------------------
// Fused: blocks <32 = top-24 per (b,h) (24-round argmax, builds repl);
// blocks 32..63 = stile_sum (2 supertile units/block).
// Selection bit-identical to two-stage bitonic: key=(fkey(v)<<32)|(L-1-idx).
// ---------------------------------------------------------------------------
__global__ __launch_bounds__(256) void topk_stile(
    const float* __restrict__ m, int* __restrict__ mtop,
    int* __restrict__ repl, const float* __restrict__ tsum,
    float* __restrict__ stsum) {
  if (blockIdx.x >= 32) {
    int unit = (blockIdx.x - 32) * 2 + (threadIdx.x >> 7);  // 0..63
    int d4 = threadIdx.x & 127;
    int s = unit & (NSUP - 1);
    int b = unit >> 4;
    float4 acc = {0.f, 0.f, 0.f, 0.f};
    const float* tb = &tsum[((size_t)b * NTILE + s * 8) * Dq + d4 * 4];
#pragma unroll
    for (int i = 0; i < 8; ++i) {
      float4 t = *(const float4*)&tb[(size_t)i * Dq];
      acc.x += t.x; acc.y += t.y; acc.z += t.z; acc.w += t.w;
    }
    *(float4*)&stsum[((size_t)b * NSUP + s) * Dq + d4 * 4] = acc;
    return;
  }
  __shared__ u64 red[2][4];
  __shared__ int mt[Uq];
  int bh = blockIdx.x;
  int tid = threadIdx.x, wave = tid >> 6, lane = tid & 63;
  u64 keys[TKCH];
#pragma unroll
  for (int c = 0; c < TKCH; ++c) {
    int gidx = c * 256 + tid;
    float v = m[(size_t)bh * Lq + gidx];
    keys[c] = ((u64)fkey(v) << 32) | (u64)(Lq - 1 - gidx);
  }
#pragma unroll 1
  for (int it = 0; it < Uq; ++it) {
    u64 lb = keys[0];
#pragma unroll
    for (int c = 1; c < TKCH; ++c) lb = keys[c] > lb ? keys[c] : lb;
#pragma unroll
    for (int off = 32; off; off >>= 1) {
      u64 o = __shfl_xor(lb, off, 64);
      lb = o > lb ? o : lb;
    }
    int p = it & 1;
    if (lane == 0) red[p][wave] = lb;
    __syncthreads();
    u64 w0 = red[p][0] > red[p][1] ? red[p][0] : red[p][1];
    u64 w1 = red[p][2] > red[p][3] ? red[p][2] : red[p][3];
    u64 win = w0 > w1 ? w0 : w1;
    if (tid == 0) {
      int idx = Lq - 1 - (int)(win & 0xFFFFFFFFull);
      mtop[bh * Uq + it] = idx;
      mt[it] = idx;
    }
#pragma unroll
    for (int c = 0; c < TKCH; ++c)
      if (keys[c] == win) keys[c] = 0;
  }
  __syncthreads();
  int* rb = &repl[(size_t)bh * Lq];
#pragma unroll
  for (int c = 0; c < TKCH; ++c) rb[c * 256 + tid] = -1;
  __syncthreads();
  if (tid < Uq) rb[mt[tid]] = tid;
}

// ---------------------------------------------------------------------------
// FUSED attention on top-24 rows: scores + chunk softmax + PV partials.
// One block per (bh, jt=128-j chunk) -> 512 blocks (2/CU). Scores stay
// bit-identical (same per-thread fp32 FMA order). V tile staged once per
// chunk, reused across all 24 u.
// ---------------------------------------------------------------------------
#define JS 64

__global__ __launch_bounds__(256) void attn_fused(
    const float* __restrict__ q, const float* __restrict__ k,
    const float* __restrict__ v, const int* __restrict__ mtop,
    float* __restrict__ pmax, float* __restrict__ psum,
    float* __restrict__ pvp) {
  __shared__ float qs[Uq][DKq + 1];   // 6.2 KB
  __shared__ float ks[JS][DKq + 1];   // 16.6 KB (reused as V tile in PV)
  __shared__ float es[Uq][132];       // 12.7 KB (132*4B: float4-aligned rows)
  __shared__ int i0s[Uq];
  int jt = blockIdx.x;   // 0..15
  int bh = blockIdx.y;   // 0..31
  int h = bh & (Hq - 1);
  int b = bh >> 3;
  int tid = threadIdx.x;
  if (tid < Uq) i0s[tid] = mtop[bh * Uq + tid];
  __syncthreads();
  int maxn = 0;
#pragma unroll
  for (int u2 = 0; u2 < Uq; ++u2) maxn = max(maxn, i0s[u2] + 1);
  int jbase0 = jt * JCH;
  if (maxn <= jbase0) return;  // uniform: no u needs this chunk

  // stage q rows (24 x 64)
  for (int s = tid; s < Uq * 16; s += 256) {
    int u = s >> 4, qd = (s & 15) * 4;
    float4 t = *(const float4*)&q[((size_t)b * Lq + i0s[u]) * Dq + h * DKq + qd];
    qs[u][qd] = t.x; qs[u][qd + 1] = t.y; qs[u][qd + 2] = t.z; qs[u][qd + 3] = t.w;
  }
  int jp = tid & 31;
  int ug = tid >> 5;
  float sreg[3][4] = {};  // [uu][sub*2 + jj]
#pragma unroll
  for (int sub = 0; sub < 2; ++sub) {
    int jb = jbase0 + sub * JS;
    __syncthreads();
    if (jb < maxn) {
      for (int s = tid; s < JS * 16; s += 256) {
        int j = s >> 4, qd = (s & 15) * 4;
        float4 t =
            *(const float4*)&k[((size_t)b * Lq + jb + j) * Dq + h * DKq + qd];
        ks[j][qd] = t.x; ks[j][qd + 1] = t.y;
        ks[j][qd + 2] = t.z; ks[j][qd + 3] = t.w;
      }
    }
    __syncthreads();
    if (jb < maxn) {
      float acc[3][2] = {};
      int j0 = jp * 2, j1 = j0 + 1;
#pragma unroll 8
      for (int d = 0; d < DKq; ++d) {
        float k0 = ks[j0][d], k1 = ks[j1][d];
#pragma unroll
        for (int uu = 0; uu < 3; ++uu) {
          float qv = qs[ug * 3 + uu][d];
          acc[uu][0] += qv * k0;
          acc[uu][1] += qv * k1;
        }
      }
#pragma unroll
      for (int uu = 0; uu < 3; ++uu) {
        sreg[uu][sub * 2] = acc[uu][0];
        sreg[uu][sub * 2 + 1] = acc[uu][1];
      }
    }
  }

  // per-u chunk softmax (32-lane groups; lanes of group share ug)
  const float scale = 0.044194173824159216f;  // 1/sqrt(512)
#pragma unroll
  for (int uu = 0; uu < 3; ++uu) {
    int u = ug * 3 + uu;
    int lu = i0s[u];
    float sv[4];
    float mx = -INFINITY;
#pragma unroll
    for (int t = 0; t < 4; ++t) {
      int jl = (t >> 1) * JS + jp * 2 + (t & 1);
      float x = sreg[uu][t] * scale;
      bool ok = (jbase0 + jl) <= lu;  // causal: j < n
      x = ok ? x : -INFINITY;
      sv[t] = x;
      mx = fmaxf(mx, x);
    }
#pragma unroll
    for (int off = 16; off; off >>= 1) mx = fmaxf(mx, __shfl_xor(mx, off, 64));
    float sm = 0.f;
#pragma unroll
    for (int t = 0; t < 4; ++t) {
      int jl = (t >> 1) * JS + jp * 2 + (t & 1);
      float e = (sv[t] == -INFINITY) ? 0.f : __expf(sv[t] - mx);
      es[u][jl] = e;
      sm += e;
    }
#pragma unroll
    for (int off = 16; off; off >>= 1) sm += __shfl_xor(sm, off, 64);
    if (jp == 0) {
      int blku = bh * Uq + u;
      pmax[blku * NCH + jt] = mx;   // garbage(-inf) chunks are never read
      psum[blku * NCH + jt] = sm;
    }
  }

  // PV: stage V sub-tile once, reuse across all 24 u. wave w owns u=w*6..+5
  int wv = tid >> 6, lane = tid & 63;
  float a6[6] = {};
#pragma unroll
  for (int sub = 0; sub < 2; ++sub) {
    int jb = jbase0 + sub * JS;
    __syncthreads();  // prev sub's reads done (and es complete before sub 0)
    if (jb < maxn) {
      for (int s = tid; s < JS * 16; s += 256) {
        int j = s >> 4, qd = (s & 15) * 4;
        float4 t =
            *(const float4*)&v[((size_t)b * Lq + jb + j) * Dq + h * DKq + qd];
        ks[j][qd] = t.x; ks[j][qd + 1] = t.y;
        ks[j][qd + 2] = t.z; ks[j][qd + 3] = t.w;
      }
    }
    __syncthreads();
    if (jb < maxn) {
#pragma unroll 4
      for (int j = 0; j < JS; j += 4) {
        float v0 = ks[j][lane], v1 = ks[j + 1][lane];
        float v2 = ks[j + 2][lane], v3 = ks[j + 3][lane];
#pragma unroll
        for (int uu = 0; uu < 6; ++uu) {
          float4 ee = *(const float4*)&es[wv * 6 + uu][sub * JS + j];
          a6[uu] += ee.x * v0 + ee.y * v1 + ee.z * v2 + ee.w * v3;
        }
      }
    }
  }
#pragma unroll
  for (int uu = 0; uu < 6; ++uu) {
    int blku = bh * Uq + wv * 6 + uu;
    pvp[((size_t)blku * NCH + jt) * DKq + lane] = a6[uu];
  }
}

// ---------------------------------------------------------------------------
// build_context: two-level exclusive prefix (<=22 loads), inline softmax
// combine at replaced rows, bf16 out.
// ---------------------------------------------------------------------------
__global__ __launch_bounds__(128) void build_context(
    const float* __restrict__ v, const float* __restrict__ tsum,
    const float* __restrict__ stsum, const int* __restrict__ repl,
    const float* __restrict__ pmax, const float* __restrict__ psum,
    const float* __restrict__ pvp, ushort_t* __restrict__ ctxh) {
  int blk = blockIdx.x;  // b*NTILE + tile
  int tile = blk & (NTILE - 1);
  int b = blk >> 7;
  int d4 = threadIdx.x;          // float4 column slice
  int h = d4 >> 4;               // (d4*4)>>6
  int sup = tile >> 3;
  float4 run = {0.f, 0.f, 0.f, 0.f};
  const float* sb = &stsum[(size_t)b * NSUP * Dq + d4 * 4];
  for (int s = 0; s < sup; ++s) {
    float4 t = *(const float4*)&sb[(size_t)s * Dq];
    run.x += t.x; run.y += t.y; run.z += t.z; run.w += t.w;
  }
  const float* tb = &tsum[((size_t)b * NTILE + sup * 8) * Dq + d4 * 4];
  int rem = tile & 7;
  for (int i = 0; i < rem; ++i) {
    float4 t = *(const float4*)&tb[(size_t)i * Dq];
    run.x += t.x; run.y += t.y; run.z += t.z; run.w += t.w;
  }
  const int* replb = &repl[(size_t)(b * Hq + h) * Lq + tile * TSCAN];
  const float* vb = &v[((size_t)b * Lq + tile * TSCAN) * Dq + d4 * 4];
  ushort_t* cb = &ctxh[((size_t)b * Lq + tile * TSCAN) * Dq + d4 * 4];
#pragma unroll
  for (int r = 0; r < TSCAN; ++r) {
    float4 x = *(const float4*)&vb[(size_t)r * Dq];
    run.x += x.x; run.y += x.y; run.z += x.z; run.w += x.w;
    int u = replb[r];
    float4 val = run;
    if (u >= 0) {
      // inline softmax combine: l == mtop[u]  =>  n = l+1
      int l = tile * TSCAN + r;
      int blku = (b * Hq + h) * Uq + u;
      int nc = (l + JCH) / JCH;  // ceil((l+1)/JCH)
      float gmax = -INFINITY;
      for (int c = 0; c < nc; ++c) gmax = fmaxf(gmax, pmax[blku * NCH + c]);
      float tot = 0.f;
      float4 acc = {0.f, 0.f, 0.f, 0.f};
      for (int c = 0; c < nc; ++c) {
        float wgt = __expf(pmax[blku * NCH + c] - gmax);
        tot += psum[blku * NCH + c] * wgt;
        float4 pv = *(const float4*)&pvp[((size_t)blku * NCH + c) * DKq +
                                         (d4 & 15) * 4];
        acc.x += pv.x * wgt; acc.y += pv.y * wgt;
        acc.z += pv.z * wgt; acc.w += pv.w * wgt;
      }
      float inv = 1.0f / tot;
      val.x = acc.x * inv; val.y = acc.y * inv;
      val.z = acc.z * inv; val.w = acc.w * inv;
    }
    ushort4 o = {bf16_rne(val.x), bf16_rne(val.y), bf16_rne(val.z),
                 bf16_rne(val.w)};
    *(ushort4*)&cb[(size_t)r * Dq] = o;
  }
}

// ---------------------------------------------------------------------------
extern "C" void kernel_launch(void* const* d_in, const int* in_sizes, int n_in,
                              void* d_out, int out_size, void* d_ws,
                              size_t ws_size, hipStream_t stream) {
  const float* queries = (const float*)d_in[0];
  const float* keys    = (const float*)d_in[1];
  const float* values  = (const float*)d_in[2];
  const int*   idxs    = (const int*)d_in[3];
  const float* Wq = (const float*)d_in[4];
  const float* bq = (const float*)d_in[5];
  const float* Wk = (const float*)d_in[6];
  const float* bk = (const float*)d_in[7];
  const float* Wv = (const float*)d_in[8];
  const float* bv = (const float*)d_in[9];
  const float* Wo = (const float*)d_in[10];
  const float* bo = (const float*)d_in[11];
  float* out = (float*)d_out;

  const size_t BLD = (size_t)Bq * Lq * Dq;  // 4,194,304
  char* w = (char*)d_ws;
  float* q    = (float*)w; w += BLD * 4;
  float* k    = (float*)w; w += BLD * 4;
  float* v    = (float*)w; w += BLD * 4;
  float* m    = (float*)w; w += (size_t)Bq * Hq * Lq * 4;
  float* tsum = (float*)w; w += (size_t)Bq * NTILE * Dq * 4;
  float* stsum= (float*)w; w += (size_t)Bq * NSUP * Dq * 4;
  int* mtop   = (int*)w;   w += Bq * Hq * Uq * 4;
  int* repl   = (int*)w;   w += (size_t)Bq * Hq * Lq * 4;
  float* pmax = (float*)w; w += (size_t)Bq * Hq * Uq * NCH * 4;
  float* psum = (float*)w; w += (size_t)Bq * Hq * Uq * NCH * 4;
  float* pvp  = (float*)w; w += (size_t)Bq * Hq * Uq * NCH * DKq * 4;
  ushort_t* ctxh = (ushort_t*)w; w += BLD * 2;  // bf16 context
  const size_t WSZ = 512 * 512;
  ushort_t* Wqh = (ushort_t*)w; w += WSZ * 2;
  ushort_t* Wql = (ushort_t*)w; w += WSZ * 2;
  ushort_t* Wkh = (ushort_t*)w; w += WSZ * 2;
  ushort_t* Wkl = (ushort_t*)w; w += WSZ * 2;
  ushort_t* Wvh = (ushort_t*)w; w += WSZ * 2;
  ushort_t* Woh = (ushort_t*)w; w += WSZ * 2;

  // weight transpose + hi/lo cast (activation cast is fused into gemm_qkv)
  {
    dim3 tgrid(16, 16, 4);
    prep_w<<<tgrid, 256, 0, stream>>>(Wq, Wk, Wv, Wo, Wqh, Wql, Wkh, Wkl,
                                      Wvh, Woh);
  }

  // fused Q/K/V projections (128x128 tiles; A = raw fp32 + in-kernel cast)
  {
    dim3 ggrid(64, 4, 3);  // M=8192/128, N=512/128, z = Q/K/V
    gemm_qkv<<<ggrid, 256, 0, stream>>>(queries, keys, values, Wqh, Wql,
                                        Wkh, Wkl, Wvh, bq, bk, bv, q, k, v);
  }

  // sparsity metric + v tile sums (independent, one launch)
  compute_m_tiles<<<4096 + 256, 256, 0, stream>>>(q, k, idxs, m, v, tsum);

  // fused top-k (builds repl) + supertile sums (independent, one launch)
  topk_stile<<<64, 256, 0, stream>>>(m, mtop, repl, tsum, stsum);

  // fused scores + softmax + PV partials (128-j chunks, 512 blocks)
  {
    dim3 agrid(Lq / JCH, Bq * Hq);  // (16, 32)
    attn_fused<<<agrid, 256, 0, stream>>>(q, k, v, mtop, pmax, psum, pvp);
  }

  // cumsum context with two-level prefix + inline combine
  build_context<<<Bq * NTILE, 128, 0, stream>>>(v, tsum, stsum, repl, pmax,
                                                psum, pvp, ctxh);

  // output projection (plain bf16, 128x128 tiles, swizzled LDS)
  {
    dim3 ggrid(64, 4);
    gemm_bf16<<<ggrid, 256, 0, stream>>>(ctxh, Woh, bo, out);
  }
}

// Round 7
// 250.230 us; speedup vs baseline: 1.0593x; 1.0494x over previous
//
#include <hip/hip_runtime.h>
#include <hip/hip_bf16.h>
#include <math.h>

#define Bq 4
#define Lq 2048
#define Dq 512
#define Hq 8
#define DKq 64
#define Uq 24
#define TSCAN 16
#define NTILE (Lq / TSCAN)   // 128
#define NSUP 16              // supertiles (8 tiles each)
#define JCH 128              // softmax j-chunk
#define NCH (Lq / JCH)       // 16
#define TKCH 8               // m-chunks per thread in topk (2048/256)

typedef unsigned short ushort_t;
typedef unsigned long long u64;
typedef __attribute__((ext_vector_type(8))) short bfrag8;   // 8 bf16 (4 VGPRs)
typedef __attribute__((ext_vector_type(4))) float facc4;    // MFMA accumulator

__device__ inline ushort_t bf16_rne(float f) {
  unsigned u = __float_as_uint(f);
  u += 0x7FFF + ((u >> 16) & 1);
  return (ushort_t)(u >> 16);
}
__device__ inline float bf16f(ushort_t h) {
  return __uint_as_float(((unsigned)h) << 16);
}
// monotone float -> uint map (no NaNs in inputs)
__device__ inline unsigned fkey(float f) {
  unsigned u = __float_as_uint(f);
  return (u & 0x80000000u) ? ~u : (u | 0x80000000u);
}
// async global->LDS, 16B per lane (lds dest = wave base + lane*16)
__device__ __forceinline__ void gl2lds16(const void* g, void* l) {
  __builtin_amdgcn_global_load_lds(
      (const __attribute__((address_space(1))) unsigned*)g,
      (__attribute__((address_space(3))) unsigned*)l, 16, 0, 0);
}

// ---------------------------------------------------------------------------
// prep_all: ONE launch for all input prep.
// y=0: q->hi/lo, y=1: k->hi/lo, y=2: v->hi (activation casts)
// y=3: weight transpose+cast (first 1024 blocks; z=bx>>8 picks W)
// ---------------------------------------------------------------------------
__global__ __launch_bounds__(256) void prep_all(
    const float* __restrict__ xq, const float* __restrict__ xk,
    const float* __restrict__ xv, ushort_t* __restrict__ qh,
    ushort_t* __restrict__ ql, ushort_t* __restrict__ kh,
    ushort_t* __restrict__ kl, ushort_t* __restrict__ vh,
    const float* __restrict__ W0, const float* __restrict__ W1,
    const float* __restrict__ W2, const float* __restrict__ W3,
    ushort_t* __restrict__ T0h, ushort_t* __restrict__ T0l,
    ushort_t* __restrict__ T1h, ushort_t* __restrict__ T1l,
    ushort_t* __restrict__ T2h, ushort_t* __restrict__ T3h) {
  __shared__ float tile[32][33];
  int y = blockIdx.y;
  if (y < 3) {
    const float* x = y == 0 ? xq : (y == 1 ? xk : xv);
    ushort_t* hi = y == 0 ? qh : (y == 1 ? kh : vh);
    ushort_t* lo = y == 0 ? ql : kl;  // unused for y==2
    int t = blockIdx.x * 256 + threadIdx.x;
    float4 v = *(const float4*)&x[(size_t)t * 4];
    ushort_t h0 = bf16_rne(v.x), h1 = bf16_rne(v.y), h2 = bf16_rne(v.z),
             h3 = bf16_rne(v.w);
    ushort4 hh = {h0, h1, h2, h3};
    *(ushort4*)&hi[(size_t)t * 4] = hh;
    if (y < 2) {
      ushort4 ll = {bf16_rne(v.x - bf16f(h0)), bf16_rne(v.y - bf16f(h1)),
                    bf16_rne(v.z - bf16f(h2)), bf16_rne(v.w - bf16f(h3))};
      *(ushort4*)&lo[(size_t)t * 4] = ll;
    }
    return;
  }
  // weight transpose path: 1024 working blocks
  int id = blockIdx.x;
  if (id >= 1024) return;
  int z = id >> 8;
  const float* W = z == 0 ? W0 : (z == 1 ? W1 : (z == 2 ? W2 : W3));
  ushort_t* Th = z == 0 ? T0h : (z == 1 ? T1h : (z == 2 ? T2h : T3h));
  ushort_t* Tl = z == 0 ? T0l : (z == 1 ? T1l : nullptr);
  int k0 = ((id >> 4) & 15) * 32, n0 = (id & 15) * 32;
  int tx = threadIdx.x & 31, ty = threadIdx.x >> 5;  // ty 0..7
  for (int r = ty; r < 32; r += 8)
    tile[tx][r] = W[(size_t)(k0 + r) * 512 + n0 + tx];
  __syncthreads();
  for (int r = ty; r < 32; r += 8) {
    float v = tile[r][tx];
    ushort_t h = bf16_rne(v);
    Th[(size_t)(n0 + r) * 512 + k0 + tx] = h;
    if (Tl) Tl[(size_t)(n0 + r) * 512 + k0 + tx] = bf16_rne(v - bf16f(h));
  }
}

// ---------------------------------------------------------------------------
// Fused Q/K/V projection GEMM, 128x128 tile, 4 waves x (64x64).
// z=0: Q (split-bf16), z=1: K (split), z=2: V (plain hi).
// XOR-swizzled LDS chunks; global_load_lds dest stays lane*16 contiguous.
// (R3 tsum epilogue / R5 64-tile / R6 in-kernel cast all REVERTED: each
// regressed; this is the measured-best ~40us configuration.)
// ---------------------------------------------------------------------------
__global__ __launch_bounds__(256) void gemm_qkv(
    const ushort_t* __restrict__ Aqh, const ushort_t* __restrict__ Aql,
    const ushort_t* __restrict__ Akh, const ushort_t* __restrict__ Akl,
    const ushort_t* __restrict__ Avh,
    const ushort_t* __restrict__ Wqh, const ushort_t* __restrict__ Wql,
    const ushort_t* __restrict__ Wkh, const ushort_t* __restrict__ Wkl,
    const ushort_t* __restrict__ Wvh,
    const float* __restrict__ bq, const float* __restrict__ bk,
    const float* __restrict__ bv,
    float* __restrict__ qo, float* __restrict__ ko, float* __restrict__ vo) {
  __shared__ ushort_t Ash[128][32], Asl[128][32];  // 8 KB each
  __shared__ ushort_t Bsh[128][32], Bsl[128][32];
  int which = blockIdx.z;
  const ushort_t* Ah = which == 0 ? Aqh : (which == 1 ? Akh : Avh);
  const ushort_t* Al = which == 0 ? Aql : Akl;  // unused for V
  const ushort_t* Bh = which == 0 ? Wqh : (which == 1 ? Wkh : Wvh);
  const ushort_t* Bl = which == 0 ? Wql : Wkl;
  const float* bias = which == 0 ? bq : (which == 1 ? bk : bv);
  float* C = which == 0 ? qo : (which == 1 ? ko : vo);
  const bool split = which < 2;

  int bm = blockIdx.x, bn = blockIdx.y;
  int tid = threadIdx.x;
  int wave = tid >> 6, lane = tid & 63;
  int wm = (wave & 1) * 64, wn = (wave >> 1) * 64;
  int quad = lane >> 4, lm = lane & 15;
  int srow = tid >> 2;                                  // staging row (p=0)
  int slc = (((tid & 3) ^ ((tid >> 3) & 3))) * 8;       // logical chunk (global src)
  int sphys = (tid & 3) * 8;                            // physical chunk (LDS dest)
  int rsw = (quad ^ ((lm >> 1) & 3)) * 8;               // fragment read chunk
  facc4 acc[4][4] = {};

  for (int k0 = 0; k0 < 512; k0 += 32) {
#pragma unroll
    for (int p = 0; p < 2; ++p) {
      int row = srow + p * 64;
      size_t ga = (size_t)(bm * 128 + row) * 512 + k0 + slc;
      size_t gb = (size_t)(bn * 128 + row) * 512 + k0 + slc;
      gl2lds16(&Ah[ga], &Ash[row][sphys]);
      gl2lds16(&Bh[gb], &Bsh[row][sphys]);
      if (split) {
        gl2lds16(&Al[ga], &Asl[row][sphys]);
        gl2lds16(&Bl[gb], &Bsl[row][sphys]);
      }
    }
    __syncthreads();
    bfrag8 afh[4], afl[4], bfh[4], bfl[4];
#pragma unroll
    for (int mt = 0; mt < 4; ++mt) {
      afh[mt] = *(bfrag8*)&Ash[wm + mt * 16 + lm][rsw];
      if (split) afl[mt] = *(bfrag8*)&Asl[wm + mt * 16 + lm][rsw];
    }
#pragma unroll
    for (int nt = 0; nt < 4; ++nt) {
      bfh[nt] = *(bfrag8*)&Bsh[wn + nt * 16 + lm][rsw];
      if (split) bfl[nt] = *(bfrag8*)&Bsl[wn + nt * 16 + lm][rsw];
    }
#pragma unroll
    for (int mt = 0; mt < 4; ++mt)
#pragma unroll
      for (int nt = 0; nt < 4; ++nt) {
        facc4 a = acc[mt][nt];
        a = __builtin_amdgcn_mfma_f32_16x16x32_bf16(afh[mt], bfh[nt], a, 0, 0, 0);
        if (split) {
          a = __builtin_amdgcn_mfma_f32_16x16x32_bf16(afl[mt], bfh[nt], a, 0, 0, 0);
          a = __builtin_amdgcn_mfma_f32_16x16x32_bf16(afh[mt], bfl[nt], a, 0, 0, 0);
        }
        acc[mt][nt] = a;
      }
    __syncthreads();
  }
#pragma unroll
  for (int mt = 0; mt < 4; ++mt)
#pragma unroll
    for (int nt = 0; nt < 4; ++nt) {
      int col = bn * 128 + wn + nt * 16 + lm;
      float bv2 = bias[col];
#pragma unroll
      for (int r = 0; r < 4; ++r) {
        int row = bm * 128 + wm + mt * 16 + quad * 4 + r;
        C[(size_t)row * 512 + col] = acc[mt][nt][r] + bv2;
      }
    }
}

// ---------------------------------------------------------------------------
// bf16 MFMA GEMM (hi only): out projection, 128x128 tile, swizzled LDS
// ---------------------------------------------------------------------------
__global__ __launch_bounds__(256) void gemm_bf16(
    const ushort_t* __restrict__ A, const ushort_t* __restrict__ Bt,
    const float* __restrict__ bias, float* __restrict__ C) {
  __shared__ ushort_t As[128][32];
  __shared__ ushort_t Bs[128][32];
  int bm = blockIdx.x, bn = blockIdx.y;
  int tid = threadIdx.x;
  int wave = tid >> 6, lane = tid & 63;
  int wm = (wave & 1) * 64, wn = (wave >> 1) * 64;
  int quad = lane >> 4, lm = lane & 15;
  int srow = tid >> 2;
  int slc = (((tid & 3) ^ ((tid >> 3) & 3))) * 8;
  int sphys = (tid & 3) * 8;
  int rsw = (quad ^ ((lm >> 1) & 3)) * 8;
  facc4 acc[4][4] = {};

  for (int k0 = 0; k0 < 512; k0 += 32) {
#pragma unroll
    for (int p = 0; p < 2; ++p) {
      int row = srow + p * 64;
      gl2lds16(&A[(size_t)(bm * 128 + row) * 512 + k0 + slc], &As[row][sphys]);
      gl2lds16(&Bt[(size_t)(bn * 128 + row) * 512 + k0 + slc], &Bs[row][sphys]);
    }
    __syncthreads();
    bfrag8 af[4], bf[4];
#pragma unroll
    for (int mt = 0; mt < 4; ++mt)
      af[mt] = *(bfrag8*)&As[wm + mt * 16 + lm][rsw];
#pragma unroll
    for (int nt = 0; nt < 4; ++nt)
      bf[nt] = *(bfrag8*)&Bs[wn + nt * 16 + lm][rsw];
#pragma unroll
    for (int mt = 0; mt < 4; ++mt)
#pragma unroll
      for (int nt = 0; nt < 4; ++nt)
        acc[mt][nt] = __builtin_amdgcn_mfma_f32_16x16x32_bf16(
            af[mt], bf[nt], acc[mt][nt], 0, 0, 0);
    __syncthreads();
  }
#pragma unroll
  for (int mt = 0; mt < 4; ++mt)
#pragma unroll
    for (int nt = 0; nt < 4; ++nt) {
      int col = bn * 128 + wn + nt * 16 + lm;
      float bv = bias[col];
#pragma unroll
      for (int r = 0; r < 4; ++r) {
        int row = bm * 128 + wm + mt * 16 + quad * 4 + r;
        C[(size_t)row * 512 + col] = acc[mt][nt][r] + bv;
      }
    }
}

// ---------------------------------------------------------------------------
// Fused: blocks <4096 = compute_m; blocks >=4096 = tile_sum (2 tiles/block).
// m[b,h,l] = max_s(q.k_sample) - sum_s(q.k_sample)/L  (bit-exact selection)
// NEW (R7): XCD-aware block remap for the k-gather. Dispatch round-robins
// blockIdx over 8 XCDs; remap so XCD-pair (2b, 2b+1) serves only batch b,
// shrinking the per-XCD gather working set 64MB -> 16MB (L2 hit 6% -> ~25%).
// Pure bijection, per-slot work bit-identical -> selection unchanged.
// ---------------------------------------------------------------------------
__global__ __launch_bounds__(256) void compute_m_tiles(
    const float* __restrict__ q, const float* __restrict__ k,
    const int* __restrict__ idxs, float* __restrict__ m,
    const float* __restrict__ v, float* __restrict__ tsum) {
  int bx = blockIdx.x;
  if (bx >= 4096) {
    // tile_sum: 512 units, 2 per block
    int unit = (bx - 4096) * 2 + (threadIdx.x >> 7);
    int d4 = threadIdx.x & 127;
    int tile = unit & (NTILE - 1);
    int b = unit >> 7;
    float4 s = {0.f, 0.f, 0.f, 0.f};
    const float* base = &v[((size_t)b * Lq + tile * TSCAN) * Dq + d4 * 4];
#pragma unroll
    for (int r = 0; r < TSCAN; ++r) {
      float4 x = *(const float4*)&base[(size_t)r * Dq];
      s.x += x.x; s.y += x.y; s.z += x.z; s.w += x.w;
    }
    *(float4*)&tsum[((size_t)b * NTILE + tile) * Dq + d4 * 4] = s;
    return;
  }
  // XCD remap: xcd = bx%8 -> batch b = xcd>>1; i = within-batch block index.
  int xcd = bx & 7;
  int bb = xcd >> 1;                       // batch 0..3
  int i = ((bx >> 3) << 1) | (xcd & 1);    // 0..1023
  int u = bb * 1024 + i;                   // logical block (b-major)
  int wave = threadIdx.x >> 6, lane = threadIdx.x & 63;
  int lq = lane >> 4, dq = lane & 15;
  int slot = u * 16 + wave * 4 + lq;       // (b,h,l) flat, b == bb
  int l = slot & (Lq - 1);
  int bh = slot >> 11;
  int h = bh & (Hq - 1), b = bh >> 3;
  float4 qv = *(const float4*)&q[((size_t)b * Lq + l) * Dq + h * DKq + dq * 4];
  const float* kb = &k[(size_t)b * Lq * Dq + h * DKq + dq * 4];
  const int* ib = &idxs[l * Uq];
  float mx = -INFINITY, sm = 0.f;
#pragma unroll
  for (int s = 0; s < Uq; ++s) {
    int j = ib[s];
    float4 kv = *(const float4*)&kb[(size_t)j * Dq];
    float p = qv.x * kv.x + qv.y * kv.y + qv.z * kv.z + qv.w * kv.w;
    p += __shfl_xor(p, 1, 64);
    p += __shfl_xor(p, 2, 64);
    p += __shfl_xor(p, 4, 64);
    p += __shfl_xor(p, 8, 64);
    mx = fmaxf(mx, p);
    sm += p;
  }
  if (dq == 0) m[slot] = mx - sm * (1.0f / Lq);
}

// ---------------------------------------------------------------------------
// Fused: blocks <32 = top-24 per (b,h) (24-round argmax, builds repl);
// blocks 32..63 = stile_sum (2 supertile units/block).
// Selection bit-identical to two-stage bitonic: key=(fkey(v)<<32)|(L-1-idx).
// ---------------------------------------------------------------------------
__global__ __launch_bounds__(256) void topk_stile(
    const float* __restrict__ m, int* __restrict__ mtop,
    int* __restrict__ repl, const float* __restrict__ tsum,
    float* __restrict__ stsum) {
  if (blockIdx.x >= 32) {
    int unit = (blockIdx.x - 32) * 2 + (threadIdx.x >> 7);  // 0..63
    int d4 = threadIdx.x & 127;
    int s = unit & (NSUP - 1);
    int b = unit >> 4;
    float4 acc = {0.f, 0.f, 0.f, 0.f};
    const float* tb = &tsum[((size_t)b * NTILE + s * 8) * Dq + d4 * 4];
#pragma unroll
    for (int i = 0; i < 8; ++i) {
      float4 t = *(const float4*)&tb[(size_t)i * Dq];
      acc.x += t.x; acc.y += t.y; acc.z += t.z; acc.w += t.w;
    }
    *(float4*)&stsum[((size_t)b * NSUP + s) * Dq + d4 * 4] = acc;
    return;
  }
  __shared__ u64 red[2][4];
  __shared__ int mt[Uq];
  int bh = blockIdx.x;
  int tid = threadIdx.x, wave = tid >> 6, lane = tid & 63;
  u64 keys[TKCH];
#pragma unroll
  for (int c = 0; c < TKCH; ++c) {
    int gidx = c * 256 + tid;
    float v = m[(size_t)bh * Lq + gidx];
    keys[c] = ((u64)fkey(v) << 32) | (u64)(Lq - 1 - gidx);
  }
#pragma unroll 1
  for (int it = 0; it < Uq; ++it) {
    u64 lb = keys[0];
#pragma unroll
    for (int c = 1; c < TKCH; ++c) lb = keys[c] > lb ? keys[c] : lb;
#pragma unroll
    for (int off = 32; off; off >>= 1) {
      u64 o = __shfl_xor(lb, off, 64);
      lb = o > lb ? o : lb;
    }
    int p = it & 1;
    if (lane == 0) red[p][wave] = lb;
    __syncthreads();
    u64 w0 = red[p][0] > red[p][1] ? red[p][0] : red[p][1];
    u64 w1 = red[p][2] > red[p][3] ? red[p][2] : red[p][3];
    u64 win = w0 > w1 ? w0 : w1;
    if (tid == 0) {
      int idx = Lq - 1 - (int)(win & 0xFFFFFFFFull);
      mtop[bh * Uq + it] = idx;
      mt[it] = idx;
    }
#pragma unroll
    for (int c = 0; c < TKCH; ++c)
      if (keys[c] == win) keys[c] = 0;
  }
  __syncthreads();
  int* rb = &repl[(size_t)bh * Lq];
#pragma unroll
  for (int c = 0; c < TKCH; ++c) rb[c * 256 + tid] = -1;
  __syncthreads();
  if (tid < Uq) rb[mt[tid]] = tid;
}

// ---------------------------------------------------------------------------
// FUSED attention on top-24 rows: scores + chunk softmax + PV partials.
// One block per (bh, jt=128-j chunk) -> 512 blocks (2/CU). Scores stay
// bit-identical (same per-thread fp32 FMA order). V tile staged once per
// chunk, reused across all 24 u.
// ---------------------------------------------------------------------------
#define JS 64

__global__ __launch_bounds__(256) void attn_fused(
    const float* __restrict__ q, const float* __restrict__ k,
    const float* __restrict__ v, const int* __restrict__ mtop,
    float* __restrict__ pmax, float* __restrict__ psum,
    float* __restrict__ pvp) {
  __shared__ float qs[Uq][DKq + 1];   // 6.2 KB
  __shared__ float ks[JS][DKq + 1];   // 16.6 KB (reused as V tile in PV)
  __shared__ float es[Uq][132];       // 12.7 KB (132*4B: float4-aligned rows)
  __shared__ int i0s[Uq];
  int jt = blockIdx.x;   // 0..15
  int bh = blockIdx.y;   // 0..31
  int h = bh & (Hq - 1);
  int b = bh >> 3;
  int tid = threadIdx.x;
  if (tid < Uq) i0s[tid] = mtop[bh * Uq + tid];
  __syncthreads();
  int maxn = 0;
#pragma unroll
  for (int u2 = 0; u2 < Uq; ++u2) maxn = max(maxn, i0s[u2] + 1);
  int jbase0 = jt * JCH;
  if (maxn <= jbase0) return;  // uniform: no u needs this chunk

  // stage q rows (24 x 64)
  for (int s = tid; s < Uq * 16; s += 256) {
    int u = s >> 4, qd = (s & 15) * 4;
    float4 t = *(const float4*)&q[((size_t)b * Lq + i0s[u]) * Dq + h * DKq + qd];
    qs[u][qd] = t.x; qs[u][qd + 1] = t.y; qs[u][qd + 2] = t.z; qs[u][qd + 3] = t.w;
  }
  int jp = tid & 31;
  int ug = tid >> 5;
  float sreg[3][4] = {};  // [uu][sub*2 + jj]
#pragma unroll
  for (int sub = 0; sub < 2; ++sub) {
    int jb = jbase0 + sub * JS;
    __syncthreads();
    if (jb < maxn) {
      for (int s = tid; s < JS * 16; s += 256) {
        int j = s >> 4, qd = (s & 15) * 4;
        float4 t =
            *(const float4*)&k[((size_t)b * Lq + jb + j) * Dq + h * DKq + qd];
        ks[j][qd] = t.x; ks[j][qd + 1] = t.y;
        ks[j][qd + 2] = t.z; ks[j][qd + 3] = t.w;
      }
    }
    __syncthreads();
    if (jb < maxn) {
      float acc[3][2] = {};
      int j0 = jp * 2, j1 = j0 + 1;
#pragma unroll 8
      for (int d = 0; d < DKq; ++d) {
        float k0 = ks[j0][d], k1 = ks[j1][d];
#pragma unroll
        for (int uu = 0; uu < 3; ++uu) {
          float qv = qs[ug * 3 + uu][d];
          acc[uu][0] += qv * k0;
          acc[uu][1] += qv * k1;
        }
      }
#pragma unroll
      for (int uu = 0; uu < 3; ++uu) {
        sreg[uu][sub * 2] = acc[uu][0];
        sreg[uu][sub * 2 + 1] = acc[uu][1];
      }
    }
  }

  // per-u chunk softmax (32-lane groups; lanes of group share ug)
  const float scale = 0.044194173824159216f;  // 1/sqrt(512)
#pragma unroll
  for (int uu = 0; uu < 3; ++uu) {
    int u = ug * 3 + uu;
    int lu = i0s[u];
    float sv[4];
    float mx = -INFINITY;
#pragma unroll
    for (int t = 0; t < 4; ++t) {
      int jl = (t >> 1) * JS + jp * 2 + (t & 1);
      float x = sreg[uu][t] * scale;
      bool ok = (jbase0 + jl) <= lu;  // causal: j < n
      x = ok ? x : -INFINITY;
      sv[t] = x;
      mx = fmaxf(mx, x);
    }
#pragma unroll
    for (int off = 16; off; off >>= 1) mx = fmaxf(mx, __shfl_xor(mx, off, 64));
    float sm = 0.f;
#pragma unroll
    for (int t = 0; t < 4; ++t) {
      int jl = (t >> 1) * JS + jp * 2 + (t & 1);
      float e = (sv[t] == -INFINITY) ? 0.f : __expf(sv[t] - mx);
      es[u][jl] = e;
      sm += e;
    }
#pragma unroll
    for (int off = 16; off; off >>= 1) sm += __shfl_xor(sm, off, 64);
    if (jp == 0) {
      int blku = bh * Uq + u;
      pmax[blku * NCH + jt] = mx;   // garbage(-inf) chunks are never read
      psum[blku * NCH + jt] = sm;
    }
  }

  // PV: stage V sub-tile once, reuse across all 24 u. wave w owns u=w*6..+5
  int wv = tid >> 6, lane = tid & 63;
  float a6[6] = {};
#pragma unroll
  for (int sub = 0; sub < 2; ++sub) {
    int jb = jbase0 + sub * JS;
    __syncthreads();  // prev sub's reads done (and es complete before sub 0)
    if (jb < maxn) {
      for (int s = tid; s < JS * 16; s += 256) {
        int j = s >> 4, qd = (s & 15) * 4;
        float4 t =
            *(const float4*)&v[((size_t)b * Lq + jb + j) * Dq + h * DKq + qd];
        ks[j][qd] = t.x; ks[j][qd + 1] = t.y;
        ks[j][qd + 2] = t.z; ks[j][qd + 3] = t.w;
      }
    }
    __syncthreads();
    if (jb < maxn) {
#pragma unroll 4
      for (int j = 0; j < JS; j += 4) {
        float v0 = ks[j][lane], v1 = ks[j + 1][lane];
        float v2 = ks[j + 2][lane], v3 = ks[j + 3][lane];
#pragma unroll
        for (int uu = 0; uu < 6; ++uu) {
          float4 ee = *(const float4*)&es[wv * 6 + uu][sub * JS + j];
          a6[uu] += ee.x * v0 + ee.y * v1 + ee.z * v2 + ee.w * v3;
        }
      }
    }
  }
#pragma unroll
  for (int uu = 0; uu < 6; ++uu) {
    int blku = bh * Uq + wv * 6 + uu;
    pvp[((size_t)blku * NCH + jt) * DKq + lane] = a6[uu];
  }
}

// ---------------------------------------------------------------------------
// build_context: two-level exclusive prefix (<=22 loads), inline softmax
// combine at replaced rows, bf16 out.
// ---------------------------------------------------------------------------
__global__ __launch_bounds__(128) void build_context(
    const float* __restrict__ v, const float* __restrict__ tsum,
    const float* __restrict__ stsum, const int* __restrict__ repl,
    const float* __restrict__ pmax, const float* __restrict__ psum,
    const float* __restrict__ pvp, ushort_t* __restrict__ ctxh) {
  int blk = blockIdx.x;  // b*NTILE + tile
  int tile = blk & (NTILE - 1);
  int b = blk >> 7;
  int d4 = threadIdx.x;          // float4 column slice
  int h = d4 >> 4;               // (d4*4)>>6
  int sup = tile >> 3;
  float4 run = {0.f, 0.f, 0.f, 0.f};
  const float* sb = &stsum[(size_t)b * NSUP * Dq + d4 * 4];
  for (int s = 0; s < sup; ++s) {
    float4 t = *(const float4*)&sb[(size_t)s * Dq];
    run.x += t.x; run.y += t.y; run.z += t.z; run.w += t.w;
  }
  const float* tb = &tsum[((size_t)b * NTILE + sup * 8) * Dq + d4 * 4];
  int rem = tile & 7;
  for (int i = 0; i < rem; ++i) {
    float4 t = *(const float4*)&tb[(size_t)i * Dq];
    run.x += t.x; run.y += t.y; run.z += t.z; run.w += t.w;
  }
  const int* replb = &repl[(size_t)(b * Hq + h) * Lq + tile * TSCAN];
  const float* vb = &v[((size_t)b * Lq + tile * TSCAN) * Dq + d4 * 4];
  ushort_t* cb = &ctxh[((size_t)b * Lq + tile * TSCAN) * Dq + d4 * 4];
#pragma unroll
  for (int r = 0; r < TSCAN; ++r) {
    float4 x = *(const float4*)&vb[(size_t)r * Dq];
    run.x += x.x; run.y += x.y; run.z += x.z; run.w += x.w;
    int u = replb[r];
    float4 val = run;
    if (u >= 0) {
      // inline softmax combine: l == mtop[u]  =>  n = l+1
      int l = tile * TSCAN + r;
      int blku = (b * Hq + h) * Uq + u;
      int nc = (l + JCH) / JCH;  // ceil((l+1)/JCH)
      float gmax = -INFINITY;
      for (int c = 0; c < nc; ++c) gmax = fmaxf(gmax, pmax[blku * NCH + c]);
      float tot = 0.f;
      float4 acc = {0.f, 0.f, 0.f, 0.f};
      for (int c = 0; c < nc; ++c) {
        float wgt = __expf(pmax[blku * NCH + c] - gmax);
        tot += psum[blku * NCH + c] * wgt;
        float4 pv = *(const float4*)&pvp[((size_t)blku * NCH + c) * DKq +
                                         (d4 & 15) * 4];
        acc.x += pv.x * wgt; acc.y += pv.y * wgt;
        acc.z += pv.z * wgt; acc.w += pv.w * wgt;
      }
      float inv = 1.0f / tot;
      val.x = acc.x * inv; val.y = acc.y * inv;
      val.z = acc.z * inv; val.w = acc.w * inv;
    }
    ushort4 o = {bf16_rne(val.x), bf16_rne(val.y), bf16_rne(val.z),
                 bf16_rne(val.w)};
    *(ushort4*)&cb[(size_t)r * Dq] = o;
  }
}

// ---------------------------------------------------------------------------
extern "C" void kernel_launch(void* const* d_in, const int* in_sizes, int n_in,
                              void* d_out, int out_size, void* d_ws,
                              size_t ws_size, hipStream_t stream) {
  const float* queries = (const float*)d_in[0];
  const float* keys    = (const float*)d_in[1];
  const float* values  = (const float*)d_in[2];
  const int*   idxs    = (const int*)d_in[3];
  const float* Wq = (const float*)d_in[4];
  const float* bq = (const float*)d_in[5];
  const float* Wk = (const float*)d_in[6];
  const float* bk = (const float*)d_in[7];
  const float* Wv = (const float*)d_in[8];
  const float* bv = (const float*)d_in[9];
  const float* Wo = (const float*)d_in[10];
  const float* bo = (const float*)d_in[11];
  float* out = (float*)d_out;

  const size_t BLD = (size_t)Bq * Lq * Dq;  // 4,194,304
  char* w = (char*)d_ws;
  float* q    = (float*)w; w += BLD * 4;
  float* k    = (float*)w; w += BLD * 4;
  float* v    = (float*)w; w += BLD * 4;
  float* m    = (float*)w; w += (size_t)Bq * Hq * Lq * 4;
  float* tsum = (float*)w; w += (size_t)Bq * NTILE * Dq * 4;
  float* stsum= (float*)w; w += (size_t)Bq * NSUP * Dq * 4;
  int* mtop   = (int*)w;   w += Bq * Hq * Uq * 4;
  int* repl   = (int*)w;   w += (size_t)Bq * Hq * Lq * 4;
  float* pmax = (float*)w; w += (size_t)Bq * Hq * Uq * NCH * 4;
  float* psum = (float*)w; w += (size_t)Bq * Hq * Uq * NCH * 4;
  float* pvp  = (float*)w; w += (size_t)Bq * Hq * Uq * NCH * DKq * 4;
  ushort_t* ctxh = (ushort_t*)w; w += BLD * 2;  // bf16 context
  ushort_t* Aqh = (ushort_t*)w; w += BLD * 2;   // pre-cast activations
  ushort_t* Aql = (ushort_t*)w; w += BLD * 2;
  ushort_t* Akh = (ushort_t*)w; w += BLD * 2;
  ushort_t* Akl = (ushort_t*)w; w += BLD * 2;
  ushort_t* Avh = (ushort_t*)w; w += BLD * 2;
  const size_t WSZ = 512 * 512;
  ushort_t* Wqh = (ushort_t*)w; w += WSZ * 2;
  ushort_t* Wql = (ushort_t*)w; w += WSZ * 2;
  ushort_t* Wkh = (ushort_t*)w; w += WSZ * 2;
  ushort_t* Wkl = (ushort_t*)w; w += WSZ * 2;
  ushort_t* Wvh = (ushort_t*)w; w += WSZ * 2;
  ushort_t* Woh = (ushort_t*)w; w += WSZ * 2;

  // all input prep (activation casts + weight transpose/cast), ONE launch
  {
    dim3 pgrid(BLD / 4 / 256, 4);  // (4096, 4); y==3 uses first 1024 blocks
    prep_all<<<pgrid, 256, 0, stream>>>(queries, keys, values, Aqh, Aql, Akh,
                                        Akl, Avh, Wq, Wk, Wv, Wo, Wqh, Wql,
                                        Wkh, Wkl, Wvh, Woh);
  }

  // fused Q/K/V projections (128x128 tiles, async LDS staging, swizzled)
  {
    dim3 ggrid(64, 4, 3);  // M=8192/128, N=512/128, z = Q/K/V
    gemm_qkv<<<ggrid, 256, 0, stream>>>(Aqh, Aql, Akh, Akl, Avh, Wqh, Wql,
                                        Wkh, Wkl, Wvh, bq, bk, bv, q, k, v);
  }

  // sparsity metric (XCD-remapped k-gather) + v tile sums, one launch
  compute_m_tiles<<<4096 + 256, 256, 0, stream>>>(q, k, idxs, m, v, tsum);

  // fused top-k (builds repl) + supertile sums (independent, one launch)
  topk_stile<<<64, 256, 0, stream>>>(m, mtop, repl, tsum, stsum);

  // fused scores + softmax + PV partials (128-j chunks, 512 blocks)
  {
    dim3 agrid(Lq / JCH, Bq * Hq);  // (16, 32)
    attn_fused<<<agrid, 256, 0, stream>>>(q, k, v, mtop, pmax, psum, pvp);
  }

  // cumsum context with two-level prefix + inline combine
  build_context<<<Bq * NTILE, 128, 0, stream>>>(v, tsum, stsum, repl, pmax,
                                                psum, pvp, ctxh);

  // output projection (plain bf16, 128x128 tiles, swizzled LDS)
  {
    dim3 ggrid(64, 4);
    gemm_bf16<<<ggrid, 256, 0, stream>>>(ctxh, Woh, bo, out);
  }
}